// Round 4
// baseline (5710.301 us; speedup 1.0000x reference)
//
#include <hip/hip_runtime.h>
#include <hip/hip_bf16.h>
#include <hip/hip_fp16.h>
#include <math.h>

#define S_LEN 256
#define BATCH 64
#define EMB 300
#define HID 512
#define NCLS 46
#define NVAL 4
#define G4H 2048
#define EPSV 1e-8f

using half8  = __attribute__((ext_vector_type(8))) _Float16;
using floatx4 = __attribute__((ext_vector_type(4))) float;

// ---------------- label norms ----------------
__global__ void k_label_norm(const float* __restrict__ label, float* __restrict__ ln) {
    int r = blockIdx.x;
    int lane = threadIdx.x;
    const float* row = label + (size_t)r * EMB;
    float ss = 0.f;
    for (int e = lane; e < EMB; e += 64) { float v = row[e]; ss += v * v; }
    #pragma unroll
    for (int off = 32; off; off >>= 1) ss += __shfl_down(ss, off);
    if (lane == 0) ln[r] = sqrtf(ss);
}

// ---------------- gather embeddings + per-position norms ----------------
__global__ __launch_bounds__(256) void k_gather(const int* __restrict__ seq,
                                                const float* __restrict__ emb,
                                                float* __restrict__ embed,
                                                float* __restrict__ en) {
    int p = blockIdx.x * 4 + (threadIdx.x >> 6);
    int lane = threadIdx.x & 63;
    int row = seq[p];
    const float4* src = (const float4*)(emb + (size_t)row * EMB);
    float4* dst = (float4*)(embed + (size_t)p * EMB);
    float ss = 0.f;
    for (int e = lane; e < EMB / 4; e += 64) {
        float4 v = src[e];
        dst[e] = v;
        ss += v.x * v.x + v.y * v.y + v.z * v.z + v.w * v.w;
    }
    #pragma unroll
    for (int off = 32; off; off >>= 1) ss += __shfl_down(ss, off);
    if (lane == 0) en[p] = sqrtf(ss);
}

// ---------------- cosine similarity + max over (s, v) ----------------
__global__ __launch_bounds__(256) void k_cos(const float* __restrict__ embed,
                                             const float* __restrict__ en,
                                             const float* __restrict__ label,
                                             const float* __restrict__ ln,
                                             float* __restrict__ match) {
    int c = blockIdx.x, b = blockIdx.y;
    __shared__ float lab[NVAL][EMB];
    __shared__ float lns[NVAL];
    __shared__ float red[256];
    int tid = threadIdx.x;
    for (int i = tid; i < NVAL * EMB; i += 256) lab[i / EMB][i % EMB] = label[(size_t)c * NVAL * EMB + i];
    if (tid < NVAL) lns[tid] = ln[c * NVAL + tid];
    __syncthreads();
    int s = tid;
    const float4* erow = (const float4*)(embed + (size_t)(s * BATCH + b) * EMB);
    float d0 = 0, d1 = 0, d2 = 0, d3 = 0;
    for (int e = 0; e < EMB / 4; e++) {
        float4 v = erow[e];
        float4 l0 = *(const float4*)&lab[0][e * 4];
        float4 l1 = *(const float4*)&lab[1][e * 4];
        float4 l2 = *(const float4*)&lab[2][e * 4];
        float4 l3 = *(const float4*)&lab[3][e * 4];
        d0 += v.x * l0.x + v.y * l0.y + v.z * l0.z + v.w * l0.w;
        d1 += v.x * l1.x + v.y * l1.y + v.z * l1.z + v.w * l1.w;
        d2 += v.x * l2.x + v.y * l2.y + v.z * l2.z + v.w * l2.w;
        d3 += v.x * l3.x + v.y * l3.y + v.z * l3.z + v.w * l3.w;
    }
    float enb = en[s * BATCH + b];
    float m = d0 / fmaxf(enb * lns[0], EPSV);
    m = fmaxf(m, d1 / fmaxf(enb * lns[1], EPSV));
    m = fmaxf(m, d2 / fmaxf(enb * lns[2], EPSV));
    m = fmaxf(m, d3 / fmaxf(enb * lns[3], EPSV));
    red[tid] = m;
    __syncthreads();
    for (int st = 128; st; st >>= 1) {
        if (tid < st) red[tid] = fmaxf(red[tid], red[tid + st]);
        __syncthreads();
    }
    if (tid == 0) match[b * NCLS + c] = red[0];
}

// ---------------- big GEMM: Y = X @ W^T + b1 + b2 (X fp32 or fp16) ----------------
template<int XH>
__global__ __launch_bounds__(256) void k_gemm(const void* __restrict__ Xv,
                                              const float* __restrict__ W,
                                              const float* __restrict__ b1,
                                              const float* __restrict__ b2,
                                              float* __restrict__ Y,
                                              int M, int N, int K) {
    __shared__ float Xs[16][132];
    __shared__ float Ws[16][132];
    int n0 = blockIdx.x * 128, m0 = blockIdx.y * 128;
    int tid = threadIdx.x;
    int tx = tid & 15, ty = tid >> 4;
    float acc[8][8] = {};
    for (int k0 = 0; k0 < K; k0 += 16) {
        #pragma unroll
        for (int i = 0; i < 8; i++) {
            int idx = i * 256 + tid;
            int r = idx >> 4, kk = idx & 15;
            int k = k0 + kk;
            float xval = 0.f, wval = 0.f;
            if (k < K) {
                if (XH) {
                    unsigned short u = ((const unsigned short*)Xv)[(size_t)(m0 + r) * K + k];
                    union { unsigned short s; _Float16 h; } cv; cv.s = u;
                    xval = (float)cv.h;
                } else {
                    xval = ((const float*)Xv)[(size_t)(m0 + r) * K + k];
                }
                wval = W[(size_t)(n0 + r) * K + k];
            }
            Xs[kk][r] = xval;
            Ws[kk][r] = wval;
        }
        __syncthreads();
        #pragma unroll
        for (int kk = 0; kk < 16; kk++) {
            float a[8], w[8];
            *(float4*)&a[0] = *(const float4*)&Xs[kk][ty * 8];
            *(float4*)&a[4] = *(const float4*)&Xs[kk][ty * 8 + 4];
            *(float4*)&w[0] = *(const float4*)&Ws[kk][tx * 8];
            *(float4*)&w[4] = *(const float4*)&Ws[kk][tx * 8 + 4];
            #pragma unroll
            for (int i = 0; i < 8; i++)
                #pragma unroll
                for (int j = 0; j < 8; j++)
                    acc[i][j] += a[i] * w[j];
        }
        __syncthreads();
    }
    float bsum[8];
    #pragma unroll
    for (int j = 0; j < 8; j++) {
        int n = n0 + tx * 8 + j;
        bsum[j] = (b1 ? b1[n] : 0.f) + (b2 ? b2[n] : 0.f);
    }
    for (int i = 0; i < 8; i++) {
        float* yp = Y + (size_t)(m0 + ty * 8 + i) * N + n0 + tx * 8;
        #pragma unroll
        for (int j = 0; j < 8; j++) yp[j] = acc[i][j] + bsum[j];
    }
}

__device__ __forceinline__ float fsigm(float x) { return 1.f / (1.f + __expf(-x)); }
__device__ __forceinline__ float ftanh(float x) {
    float e2 = __expf(-2.f * x);
    return (1.f - e2) / (1.f + e2);
}

// ---------------- persistent MFMA LSTM layer ----------------
// 32 blocks x 512 threads (8 waves). Block jg owns h-units [jg*16, jg*16+16)
// (= 64 gate-cols), all 64 batches. W fragments live in VGPRs (fp16).
// h exchanged via fp16 ring (one slot per t) with agent-scope atomics.
// Sync: per-block monotonic watermark flags (no RMW contention).
__global__ __launch_bounds__(512) void k_lstm_mfma(
    const float* __restrict__ w,          // [2048][512] w_hh
    const float* __restrict__ G,          // [256][64][2048] fp32 (x@w_ih^T + biases)
    unsigned short* __restrict__ ring,    // [256][64][512] fp16
    float* __restrict__ hlast,            // [64][512] fp32 (or nullptr)
    int* __restrict__ flags)              // [32], pre-zeroed
{
    __shared__ unsigned int smem[16384];  // 64 KB: w-staging, then gbuf (17.4 KB)
    int jg = blockIdx.x;
    int tid = threadIdx.x;
    int lane = tid & 63;
    int w8 = tid >> 6;          // wave 0..7
    int mt = w8 & 3;            // M-tile (16 batches)
    int ntp = w8 >> 2;          // N-tile pair: gates {0,1} or {2,3}
    int q8 = lane >> 4;         // k-quadrant within fragment
    int j = lane & 15;          // unit (col) within tile / A-row within M-tile

    // ---- stage w slice -> LDS fp16, XOR-swizzled [r][k] (one time) ----
    for (int it = 0; it < 16; it++) {
        int idx = it * 512 + tid;            // 8192 chunks of 8B
        int r = idx >> 7;                    // local row 0..63 (= g*16+u)
        int c = idx & 127;                   // 8B chunk within row
        int grow = (r >> 4) * 512 + jg * 16 + (r & 15);
        float4 w4 = *(const float4*)(w + (size_t)grow * 512 + c * 4);
        union { _Float16 h[4]; unsigned long long q; } pk;
        pk.h[0] = (_Float16)w4.x; pk.h[1] = (_Float16)w4.y;
        pk.h[2] = (_Float16)w4.z; pk.h[3] = (_Float16)w4.w;
        int P = r * 1024 + c * 8;
        int L = P ^ ((r & 7) << 4);
        *(unsigned long long*)((char*)smem + L) = pk.q;
    }
    __syncthreads();

    // ---- B fragments -> registers: B[ntl][kk], kk = K/32 step ----
    half8 B[2][16];
    #pragma unroll
    for (int ntl = 0; ntl < 2; ntl++) {
        int g = ntp * 2 + ntl;
        int r = g * 16 + j;
        #pragma unroll
        for (int kk = 0; kk < 16; kk++) {
            int P = r * 1024 + kk * 64 + q8 * 16;
            int L = P ^ ((r & 7) << 4);
            uint4 t4 = *(const uint4*)((const char*)smem + L);
            union { uint4 u; half8 v; } cv; cv.u = t4;
            B[ntl][kk] = cv.v;
        }
    }
    __syncthreads();
    float* gb = (float*)smem;   // gbuf [64][68] floats, reuses staging LDS

    // gate-phase mapping + register c-state
    int gm = tid >> 3;              // batch 0..63
    int gu = (tid & 7) * 2;         // local unit pair
    float c0 = 0.f, c1 = 0.f;

    int mA = mt * 16 + j;           // A-fragment global batch row
    int mC = mt * 16 + q8 * 4;      // C base row (batch)

    for (int t = 0; t < S_LEN; t++) {
        // ---- G prefetch (independent of h; issued before the poll) ----
        const float* Gt = G + (size_t)t * BATCH * G4H;
        float ga[4], gbv[4];
        #pragma unroll
        for (int r = 0; r < 4; r++) {
            ga[r]  = Gt[(size_t)(mC + r) * G4H + (ntp * 2) * 512 + jg * 16 + j];
            gbv[r] = Gt[(size_t)(mC + r) * G4H + (ntp * 2 + 1) * 512 + jg * 16 + j];
        }
        floatx4 acc0 = { ga[0], ga[1], ga[2], ga[3] };
        floatx4 acc1 = { gbv[0], gbv[1], gbv[2], gbv[3] };

        if (t > 0) {
            // ---- watermark barrier ----
            if (tid < 32) {
                int gd = 1 << 21;
                while (__hip_atomic_load(flags + tid, __ATOMIC_RELAXED,
                                         __HIP_MEMORY_SCOPE_AGENT) < t && --gd) {}
            }
            __syncthreads();

            // ---- A fragments straight from global (fp16 ring, sc1 loads) ----
            const unsigned long long* hq = (const unsigned long long*)
                (ring + (size_t)(t - 1) * BATCH * HID + (size_t)mA * HID);
            unsigned long long a0[16], a1[16];
            #pragma unroll
            for (int kk = 0; kk < 8; kk++) {
                a0[2*kk]   = __hip_atomic_load(hq + kk * 8 + q8 * 2,     __ATOMIC_RELAXED, __HIP_MEMORY_SCOPE_AGENT);
                a0[2*kk+1] = __hip_atomic_load(hq + kk * 8 + q8 * 2 + 1, __ATOMIC_RELAXED, __HIP_MEMORY_SCOPE_AGENT);
            }
            #pragma unroll
            for (int kk = 0; kk < 8; kk++) {
                int k2 = kk + 8;
                a1[2*kk]   = __hip_atomic_load(hq + k2 * 8 + q8 * 2,     __ATOMIC_RELAXED, __HIP_MEMORY_SCOPE_AGENT);
                a1[2*kk+1] = __hip_atomic_load(hq + k2 * 8 + q8 * 2 + 1, __ATOMIC_RELAXED, __HIP_MEMORY_SCOPE_AGENT);
            }
            #pragma unroll
            for (int kk = 0; kk < 8; kk++) {
                union { unsigned long long q[2]; half8 v; } af;
                af.q[0] = a0[2*kk]; af.q[1] = a0[2*kk+1];
                acc0 = __builtin_amdgcn_mfma_f32_16x16x32_f16(af.v, B[0][kk], acc0, 0, 0, 0);
                acc1 = __builtin_amdgcn_mfma_f32_16x16x32_f16(af.v, B[1][kk], acc1, 0, 0, 0);
            }
            #pragma unroll
            for (int kk = 0; kk < 8; kk++) {
                union { unsigned long long q[2]; half8 v; } af;
                af.q[0] = a1[2*kk]; af.q[1] = a1[2*kk+1];
                acc0 = __builtin_amdgcn_mfma_f32_16x16x32_f16(af.v, B[0][kk + 8], acc0, 0, 0, 0);
                acc1 = __builtin_amdgcn_mfma_f32_16x16x32_f16(af.v, B[1][kk + 8], acc1, 0, 0, 0);
            }
        }

        // ---- C -> gbuf ----
        #pragma unroll
        for (int r = 0; r < 4; r++) {
            gb[(mC + r) * 68 + (ntp * 2) * 16 + j]     = acc0[r];
            gb[(mC + r) * 68 + (ntp * 2 + 1) * 16 + j] = acc1[r];
        }
        __syncthreads();

        // ---- gates + c/h update (2 units per thread) ----
        {
            const float* bp = gb + gm * 68 + gu;
            float gi0 = bp[0],  gi1 = bp[1];
            float gf0 = bp[16], gf1 = bp[17];
            float gg0 = bp[32], gg1 = bp[33];
            float go0 = bp[48], go1 = bp[49];
            c0 = fsigm(gf0) * c0 + fsigm(gi0) * ftanh(gg0);
            c1 = fsigm(gf1) * c1 + fsigm(gi1) * ftanh(gg1);
            float hv0 = fsigm(go0) * ftanh(c0);
            float hv1 = fsigm(go1) * ftanh(c1);
            union { unsigned short s; _Float16 h; } p0, p1;
            p0.h = (_Float16)hv0; p1.h = (_Float16)hv1;
            unsigned int pk = (unsigned int)p0.s | ((unsigned int)p1.s << 16);
            unsigned int* rp = (unsigned int*)ring;
            __hip_atomic_store(rp + ((size_t)t * BATCH * HID + gm * HID + jg * 16 + gu) / 2,
                               pk, __ATOMIC_RELAXED, __HIP_MEMORY_SCOPE_AGENT);
            if (hlast != nullptr && t == S_LEN - 1) {
                hlast[gm * HID + jg * 16 + gu]     = hv0;
                hlast[gm * HID + jg * 16 + gu + 1] = hv1;
            }
        }
        __syncthreads();   // drains h stores (vmcnt) in all waves
        if (tid == 0)
            __hip_atomic_store(flags + jg, t + 1, __ATOMIC_RELAXED, __HIP_MEMORY_SCOPE_AGENT);
    }
}

// ---------------- small GEMM ----------------
__global__ void k_small(const float* __restrict__ X, const float* __restrict__ W,
                        const float* __restrict__ bias, float* __restrict__ Y,
                        int N, int K) {
    int m = blockIdx.x;
    int n = blockIdx.y * 64 + threadIdx.x;
    if (n >= N) return;
    const float* x = X + (size_t)m * K;
    const float* w = W + (size_t)n * K;
    float s = bias[n];
    for (int k = 0; k < K; k++) s += x[k] * w[k];
    Y[(size_t)m * N + n] = s;
}

// ---------------- final head ----------------
__global__ void k_final(const float* __restrict__ match, const float* __restrict__ lout,
                        const float* __restrict__ W, const float* __restrict__ bias,
                        float* __restrict__ out) {
    int m = blockIdx.x;
    int n = threadIdx.x;
    if (n >= NCLS) return;
    const float* w = W + (size_t)n * (2 * NCLS);
    float s = bias[n];
    for (int k = 0; k < NCLS; k++) s += match[m * NCLS + k] * w[k];
    for (int k = 0; k < NCLS; k++) s += lout[m * NCLS + k] * w[NCLS + k];
    out[m * NCLS + n] = s;
}

extern "C" void kernel_launch(void* const* d_in, const int* in_sizes, int n_in,
                              void* d_out, int out_size, void* d_ws, size_t ws_size,
                              hipStream_t stream) {
    (void)in_sizes; (void)n_in; (void)out_size; (void)ws_size;
    const int*   seq    = (const int*)d_in[0];
    const float* emb    = (const float*)d_in[1];
    const float* w_ih0  = (const float*)d_in[2];
    const float* w_hh0  = (const float*)d_in[3];
    const float* b_ih0  = (const float*)d_in[4];
    const float* b_hh0  = (const float*)d_in[5];
    const float* w_ih1  = (const float*)d_in[6];
    const float* w_hh1  = (const float*)d_in[7];
    const float* b_ih1  = (const float*)d_in[8];
    const float* b_hh1  = (const float*)d_in[9];
    const float* lin_w  = (const float*)d_in[10];
    const float* lin_b  = (const float*)d_in[11];
    const float* out_w  = (const float*)d_in[12];
    const float* out_b  = (const float*)d_in[13];
    const float* pred_w = (const float*)d_in[14];
    const float* pred_b = (const float*)d_in[15];
    const float* label  = (const float*)d_in[16];

    float* ws = (float*)d_ws;
    size_t o = 0;
    float* embed = ws + o; o += (size_t)S_LEN * BATCH * EMB;        // 19.7 MB
    float* Gbuf  = ws + o; o += (size_t)S_LEN * BATCH * G4H;        // 134 MB (reused by both layers)
    unsigned short* ring0 = (unsigned short*)(ws + o); o += (size_t)S_LEN * BATCH * HID / 2;  // fp16, 16.8 MB
    unsigned short* ring1 = (unsigned short*)(ws + o); o += (size_t)S_LEN * BATCH * HID / 2;  // fp16, 16.8 MB
    float* h1last = ws + o; o += (size_t)BATCH * HID;
    float* en    = ws + o; o += S_LEN * BATCH;
    float* ln    = ws + o; o += 256;
    float* match = ws + o; o += 3072;
    float* feat  = ws + o; o += (size_t)BATCH * HID;
    float* lout  = ws + o; o += 3072;
    int*   flags0 = (int*)(ws + o); o += 32;
    int*   flags1 = (int*)(ws + o); o += 32;

    hipMemsetAsync(flags0, 0, 64 * sizeof(int), stream);

    k_label_norm<<<NCLS * NVAL, 64, 0, stream>>>(label, ln);
    k_gather<<<S_LEN * BATCH / 4, 256, 0, stream>>>(seq, emb, embed, en);
    k_cos<<<dim3(NCLS, BATCH), 256, 0, stream>>>(embed, en, label, ln, match);

    // layer 0
    k_gemm<0><<<dim3(G4H / 128, S_LEN * BATCH / 128), 256, 0, stream>>>(
        embed, w_ih0, b_ih0, b_hh0, Gbuf, S_LEN * BATCH, G4H, EMB);
    k_lstm_mfma<<<32, 512, 0, stream>>>(w_hh0, Gbuf, ring0, nullptr, flags0);

    // layer 1 (input GEMM reads fp16 ring0)
    k_gemm<1><<<dim3(G4H / 128, S_LEN * BATCH / 128), 256, 0, stream>>>(
        ring0, w_ih1, b_ih1, b_hh1, Gbuf, S_LEN * BATCH, G4H, HID);
    k_lstm_mfma<<<32, 512, 0, stream>>>(w_hh1, Gbuf, ring1, h1last, flags1);

    // heads
    k_small<<<dim3(BATCH, HID / 64), 64, 0, stream>>>(h1last, lin_w, lin_b, feat, HID, HID);
    k_small<<<dim3(BATCH, 1), 64, 0, stream>>>(feat, out_w, out_b, lout, NCLS, HID);
    k_final<<<BATCH, 64, 0, stream>>>(match, lout, pred_w, pred_b, (float*)d_out);
}

// Round 5
// 2219.546 us; speedup vs baseline: 2.5727x; 2.5727x over previous
//
#include <hip/hip_runtime.h>
#include <hip/hip_bf16.h>
#include <hip/hip_fp16.h>
#include <math.h>

#define S_LEN 256
#define BATCH 64
#define EMB 300
#define HID 512
#define NCLS 46
#define NVAL 4
#define G4H 2048
#define EPSV 1e-8f

using half8  = __attribute__((ext_vector_type(8))) _Float16;
using floatx4 = __attribute__((ext_vector_type(4))) float;

// ---------------- label norms ----------------
__global__ void k_label_norm(const float* __restrict__ label, float* __restrict__ ln) {
    int r = blockIdx.x;
    int lane = threadIdx.x;
    const float* row = label + (size_t)r * EMB;
    float ss = 0.f;
    for (int e = lane; e < EMB; e += 64) { float v = row[e]; ss += v * v; }
    #pragma unroll
    for (int off = 32; off; off >>= 1) ss += __shfl_down(ss, off);
    if (lane == 0) ln[r] = sqrtf(ss);
}

// ---------------- gather embeddings + per-position norms ----------------
__global__ __launch_bounds__(256) void k_gather(const int* __restrict__ seq,
                                                const float* __restrict__ emb,
                                                float* __restrict__ embed,
                                                float* __restrict__ en) {
    int p = blockIdx.x * 4 + (threadIdx.x >> 6);
    int lane = threadIdx.x & 63;
    int row = seq[p];
    const float4* src = (const float4*)(emb + (size_t)row * EMB);
    float4* dst = (float4*)(embed + (size_t)p * EMB);
    float ss = 0.f;
    for (int e = lane; e < EMB / 4; e += 64) {
        float4 v = src[e];
        dst[e] = v;
        ss += v.x * v.x + v.y * v.y + v.z * v.z + v.w * v.w;
    }
    #pragma unroll
    for (int off = 32; off; off >>= 1) ss += __shfl_down(ss, off);
    if (lane == 0) en[p] = sqrtf(ss);
}

// ---------------- cosine similarity + max over (s, v) ----------------
__global__ __launch_bounds__(256) void k_cos(const float* __restrict__ embed,
                                             const float* __restrict__ en,
                                             const float* __restrict__ label,
                                             const float* __restrict__ ln,
                                             float* __restrict__ match) {
    int c = blockIdx.x, b = blockIdx.y;
    __shared__ float lab[NVAL][EMB];
    __shared__ float lns[NVAL];
    __shared__ float red[256];
    int tid = threadIdx.x;
    for (int i = tid; i < NVAL * EMB; i += 256) lab[i / EMB][i % EMB] = label[(size_t)c * NVAL * EMB + i];
    if (tid < NVAL) lns[tid] = ln[c * NVAL + tid];
    __syncthreads();
    int s = tid;
    const float4* erow = (const float4*)(embed + (size_t)(s * BATCH + b) * EMB);
    float d0 = 0, d1 = 0, d2 = 0, d3 = 0;
    for (int e = 0; e < EMB / 4; e++) {
        float4 v = erow[e];
        float4 l0 = *(const float4*)&lab[0][e * 4];
        float4 l1 = *(const float4*)&lab[1][e * 4];
        float4 l2 = *(const float4*)&lab[2][e * 4];
        float4 l3 = *(const float4*)&lab[3][e * 4];
        d0 += v.x * l0.x + v.y * l0.y + v.z * l0.z + v.w * l0.w;
        d1 += v.x * l1.x + v.y * l1.y + v.z * l1.z + v.w * l1.w;
        d2 += v.x * l2.x + v.y * l2.y + v.z * l2.z + v.w * l2.w;
        d3 += v.x * l3.x + v.y * l3.y + v.z * l3.z + v.w * l3.w;
    }
    float enb = en[s * BATCH + b];
    float m = d0 / fmaxf(enb * lns[0], EPSV);
    m = fmaxf(m, d1 / fmaxf(enb * lns[1], EPSV));
    m = fmaxf(m, d2 / fmaxf(enb * lns[2], EPSV));
    m = fmaxf(m, d3 / fmaxf(enb * lns[3], EPSV));
    red[tid] = m;
    __syncthreads();
    for (int st = 128; st; st >>= 1) {
        if (tid < st) red[tid] = fmaxf(red[tid], red[tid + st]);
        __syncthreads();
    }
    if (tid == 0) match[b * NCLS + c] = red[0];
}

// ---------------- big GEMM: Y = X @ W^T + b1 + b2 (X fp32 or fp16) ----------------
template<int XH>
__global__ __launch_bounds__(256) void k_gemm(const void* __restrict__ Xv,
                                              const float* __restrict__ W,
                                              const float* __restrict__ b1,
                                              const float* __restrict__ b2,
                                              float* __restrict__ Y,
                                              int M, int N, int K) {
    __shared__ float Xs[16][132];
    __shared__ float Ws[16][132];
    int n0 = blockIdx.x * 128, m0 = blockIdx.y * 128;
    int tid = threadIdx.x;
    int tx = tid & 15, ty = tid >> 4;
    float acc[8][8] = {};
    for (int k0 = 0; k0 < K; k0 += 16) {
        #pragma unroll
        for (int i = 0; i < 8; i++) {
            int idx = i * 256 + tid;
            int r = idx >> 4, kk = idx & 15;
            int k = k0 + kk;
            float xval = 0.f, wval = 0.f;
            if (k < K) {
                if (XH) {
                    unsigned short u = ((const unsigned short*)Xv)[(size_t)(m0 + r) * K + k];
                    union { unsigned short s; _Float16 h; } cv; cv.s = u;
                    xval = (float)cv.h;
                } else {
                    xval = ((const float*)Xv)[(size_t)(m0 + r) * K + k];
                }
                wval = W[(size_t)(n0 + r) * K + k];
            }
            Xs[kk][r] = xval;
            Ws[kk][r] = wval;
        }
        __syncthreads();
        #pragma unroll
        for (int kk = 0; kk < 16; kk++) {
            float a[8], w[8];
            *(float4*)&a[0] = *(const float4*)&Xs[kk][ty * 8];
            *(float4*)&a[4] = *(const float4*)&Xs[kk][ty * 8 + 4];
            *(float4*)&w[0] = *(const float4*)&Ws[kk][tx * 8];
            *(float4*)&w[4] = *(const float4*)&Ws[kk][tx * 8 + 4];
            #pragma unroll
            for (int i = 0; i < 8; i++)
                #pragma unroll
                for (int j = 0; j < 8; j++)
                    acc[i][j] += a[i] * w[j];
        }
        __syncthreads();
    }
    float bsum[8];
    #pragma unroll
    for (int j = 0; j < 8; j++) {
        int n = n0 + tx * 8 + j;
        bsum[j] = (b1 ? b1[n] : 0.f) + (b2 ? b2[n] : 0.f);
    }
    for (int i = 0; i < 8; i++) {
        float* yp = Y + (size_t)(m0 + ty * 8 + i) * N + n0 + tx * 8;
        #pragma unroll
        for (int j = 0; j < 8; j++) yp[j] = acc[i][j] + bsum[j];
    }
}

__device__ __forceinline__ float fsigm(float x) { return 1.f / (1.f + __expf(-x)); }
__device__ __forceinline__ float ftanh(float x) {
    float e2 = __expf(-2.f * x);
    return (1.f - e2) / (1.f + e2);
}

// ---------------- persistent MFMA LSTM layer, XCD-local groups ----------------
// Grid 64 blocks x 512 threads (8 waves). Group g = bid&7 (-> XCD g via round-robin
// dispatch) owns batches [g*8, g*8+8). Role r = bid>>3 owns h-units [r*64, r*64+64)
// (x4 gates = 256 gate-cols). Weights as fp16 MFMA B-frags in VGPRs (128 VGPR).
// h exchange + flags stay within the group's shared (coherent) XCD L2.
__global__ __launch_bounds__(512) void k_lstm_mfma(
    const float* __restrict__ w,          // [2048][512] w_hh
    const float* __restrict__ G,          // [256][64][2048] fp32 (x@w_ih^T + biases)
    unsigned short* __restrict__ ring,    // [256][64][512] fp16
    float* __restrict__ hlast,            // [64][512] fp32 (or nullptr)
    int* __restrict__ flags)              // [64], pre-zeroed
{
    __shared__ _Float16 hl[8][520];       // h[t-1] slice, +8 pad
    __shared__ float gbuf[8][260];        // gate preacts [batch][local col]

    int bid = blockIdx.x;
    int g = bid & 7, r = bid >> 3;
    int tid = threadIdx.x;
    int w8 = tid >> 6;            // wave 0..7
    int l = tid & 63;
    int lj = l & 15;              // col within 16-wide tile / A row
    int q8 = l >> 4;              // k-quadrant (8 contiguous k each)

    // ---- B fragments -> VGPRs (one time). Wave w8 owns local cols [w8*32, w8*32+32).
    half8 B[2][16];
    #pragma unroll
    for (int wn = 0; wn < 2; wn++) {
        int lc = w8 * 32 + wn * 16 + lj;                 // local col 0..255
        int wrow = (lc >> 6) * 512 + r * 64 + (lc & 63); // global gate-col
        #pragma unroll
        for (int kk = 0; kk < 16; kk++) {
            const float* wp = w + (size_t)wrow * 512 + kk * 32 + q8 * 8;
            float4 f0 = *(const float4*)wp;
            float4 f1 = *(const float4*)(wp + 4);
            half8 hb;
            hb[0] = (_Float16)f0.x; hb[1] = (_Float16)f0.y;
            hb[2] = (_Float16)f0.z; hb[3] = (_Float16)f0.w;
            hb[4] = (_Float16)f1.x; hb[5] = (_Float16)f1.y;
            hb[6] = (_Float16)f1.z; hb[7] = (_Float16)f1.w;
            B[wn][kk] = hb;
        }
    }

    // gate-phase mapping: thread -> (batch gb_, unit gj)
    int gb_ = tid >> 6;           // 0..7
    int gj = tid & 63;            // 0..63
    float cst = 0.f;

    for (int t = 0; t < S_LEN; t++) {
        // ---- G[t] loads issued before the poll (independent of recurrence) ----
        const float* Gp = G + ((size_t)t * BATCH + g * 8 + gb_) * G4H + r * 64 + gj;
        float gv0 = Gp[0], gv1 = Gp[512], gv2 = Gp[1024], gv3 = Gp[1536];

        floatx4 acc0 = {0.f, 0.f, 0.f, 0.f}, acc1 = {0.f, 0.f, 0.f, 0.f};
        if (t > 0) {
            // ---- watermark poll: wait for all 8 roles of this group ----
            if (tid < 8) {
                int gd = 1 << 20;
                while (__hip_atomic_load(flags + g * 8 + tid, __ATOMIC_RELAXED,
                                         __HIP_MEMORY_SCOPE_AGENT) < t && --gd) {}
            }
            __syncthreads();

            // ---- stage h[t-1] (8 x 512 fp16 = 8 KB): one 16B agent-load per thread ----
            {
                int sb = tid >> 6, sk = (tid & 63) * 8;
                const unsigned long long* src = (const unsigned long long*)
                    (ring + ((size_t)(t - 1) * BATCH + g * 8 + sb) * HID + sk);
                unsigned long long v0 = __hip_atomic_load(src,     __ATOMIC_RELAXED, __HIP_MEMORY_SCOPE_AGENT);
                unsigned long long v1 = __hip_atomic_load(src + 1, __ATOMIC_RELAXED, __HIP_MEMORY_SCOPE_AGENT);
                *(unsigned long long*)&hl[sb][sk]     = v0;
                *(unsigned long long*)&hl[sb][sk + 4] = v1;
            }
            __syncthreads();

            // ---- MFMA: full K per wave, 2 N-tiles ----
            #pragma unroll
            for (int kk = 0; kk < 16; kk++) {
                half8 A = *(const half8*)&hl[l & 7][kk * 32 + q8 * 8];
                acc0 = __builtin_amdgcn_mfma_f32_16x16x32_f16(A, B[0][kk], acc0, 0, 0, 0);
                acc1 = __builtin_amdgcn_mfma_f32_16x16x32_f16(A, B[1][kk], acc1, 0, 0, 0);
            }
            // ---- C -> gbuf (rows 0..7 valid; q8 0..1 <=> lanes l<32) ----
            if (l < 32) {
                #pragma unroll
                for (int ri = 0; ri < 4; ri++) {
                    int row = q8 * 4 + ri;
                    gbuf[row][w8 * 32 + lj]      = acc0[ri];
                    gbuf[row][w8 * 32 + 16 + lj] = acc1[ri];
                }
            }
            __syncthreads();
        }

        // ---- gates + c/h update (one (batch,unit) per thread) ----
        float s_i = gv0 + (t ? gbuf[gb_][gj]       : 0.f);
        float s_f = gv1 + (t ? gbuf[gb_][64 + gj]  : 0.f);
        float s_g = gv2 + (t ? gbuf[gb_][128 + gj] : 0.f);
        float s_o = gv3 + (t ? gbuf[gb_][192 + gj] : 0.f);
        cst = fsigm(s_f) * cst + fsigm(s_i) * ftanh(s_g);
        float hv = fsigm(s_o) * ftanh(cst);

        union { unsigned short s; _Float16 h; } cv; cv.h = (_Float16)hv;
        unsigned int mine = cv.s;
        unsigned int other = (unsigned int)__shfl_xor((int)mine, 1);
        if (!(gj & 1)) {
            unsigned int pk = (mine & 0xFFFFu) | (other << 16);
            unsigned int* rp = (unsigned int*)ring;
            __hip_atomic_store(rp + (((size_t)t * BATCH + g * 8 + gb_) * HID + r * 64 + gj) / 2,
                               pk, __ATOMIC_RELAXED, __HIP_MEMORY_SCOPE_AGENT);
        }
        if (hlast != nullptr && t == S_LEN - 1)
            hlast[(g * 8 + gb_) * HID + r * 64 + gj] = hv;

        __syncthreads();   // drains all waves' h stores (vmcnt) before publish
        if (tid == 0)
            __hip_atomic_store(flags + g * 8 + r, t + 1, __ATOMIC_RELAXED, __HIP_MEMORY_SCOPE_AGENT);
    }
}

// ---------------- small GEMM ----------------
__global__ void k_small(const float* __restrict__ X, const float* __restrict__ W,
                        const float* __restrict__ bias, float* __restrict__ Y,
                        int N, int K) {
    int m = blockIdx.x;
    int n = blockIdx.y * 64 + threadIdx.x;
    if (n >= N) return;
    const float* x = X + (size_t)m * K;
    const float* w = W + (size_t)n * K;
    float s = bias[n];
    for (int k = 0; k < K; k++) s += x[k] * w[k];
    Y[(size_t)m * N + n] = s;
}

// ---------------- final head ----------------
__global__ void k_final(const float* __restrict__ match, const float* __restrict__ lout,
                        const float* __restrict__ W, const float* __restrict__ bias,
                        float* __restrict__ out) {
    int m = blockIdx.x;
    int n = threadIdx.x;
    if (n >= NCLS) return;
    const float* w = W + (size_t)n * (2 * NCLS);
    float s = bias[n];
    for (int k = 0; k < NCLS; k++) s += match[m * NCLS + k] * w[k];
    for (int k = 0; k < NCLS; k++) s += lout[m * NCLS + k] * w[NCLS + k];
    out[m * NCLS + n] = s;
}

extern "C" void kernel_launch(void* const* d_in, const int* in_sizes, int n_in,
                              void* d_out, int out_size, void* d_ws, size_t ws_size,
                              hipStream_t stream) {
    (void)in_sizes; (void)n_in; (void)out_size; (void)ws_size;
    const int*   seq    = (const int*)d_in[0];
    const float* emb    = (const float*)d_in[1];
    const float* w_ih0  = (const float*)d_in[2];
    const float* w_hh0  = (const float*)d_in[3];
    const float* b_ih0  = (const float*)d_in[4];
    const float* b_hh0  = (const float*)d_in[5];
    const float* w_ih1  = (const float*)d_in[6];
    const float* w_hh1  = (const float*)d_in[7];
    const float* b_ih1  = (const float*)d_in[8];
    const float* b_hh1  = (const float*)d_in[9];
    const float* lin_w  = (const float*)d_in[10];
    const float* lin_b  = (const float*)d_in[11];
    const float* out_w  = (const float*)d_in[12];
    const float* out_b  = (const float*)d_in[13];
    const float* pred_w = (const float*)d_in[14];
    const float* pred_b = (const float*)d_in[15];
    const float* label  = (const float*)d_in[16];

    float* ws = (float*)d_ws;
    size_t o = 0;
    float* embed = ws + o; o += (size_t)S_LEN * BATCH * EMB;        // 19.7 MB
    float* Gbuf  = ws + o; o += (size_t)S_LEN * BATCH * G4H;        // 134 MB (reused by both layers)
    unsigned short* ring0 = (unsigned short*)(ws + o); o += (size_t)S_LEN * BATCH * HID / 2;  // fp16
    unsigned short* ring1 = (unsigned short*)(ws + o); o += (size_t)S_LEN * BATCH * HID / 2;  // fp16
    float* h1last = ws + o; o += (size_t)BATCH * HID;
    float* en    = ws + o; o += S_LEN * BATCH;
    float* ln    = ws + o; o += 256;
    float* match = ws + o; o += 3072;
    float* feat  = ws + o; o += (size_t)BATCH * HID;
    float* lout  = ws + o; o += 3072;
    int*   flags0 = (int*)(ws + o); o += 64;
    int*   flags1 = (int*)(ws + o); o += 64;

    hipMemsetAsync(flags0, 0, 128 * sizeof(int), stream);

    k_label_norm<<<NCLS * NVAL, 64, 0, stream>>>(label, ln);
    k_gather<<<S_LEN * BATCH / 4, 256, 0, stream>>>(seq, emb, embed, en);
    k_cos<<<dim3(NCLS, BATCH), 256, 0, stream>>>(embed, en, label, ln, match);

    // layer 0
    k_gemm<0><<<dim3(G4H / 128, S_LEN * BATCH / 128), 256, 0, stream>>>(
        embed, w_ih0, b_ih0, b_hh0, Gbuf, S_LEN * BATCH, G4H, EMB);
    k_lstm_mfma<<<64, 512, 0, stream>>>(w_hh0, Gbuf, ring0, nullptr, flags0);

    // layer 1 (input GEMM reads fp16 ring0)
    k_gemm<1><<<dim3(G4H / 128, S_LEN * BATCH / 128), 256, 0, stream>>>(
        ring0, w_ih1, b_ih1, b_hh1, Gbuf, S_LEN * BATCH, G4H, HID);
    k_lstm_mfma<<<64, 512, 0, stream>>>(w_hh1, Gbuf, ring1, h1last, flags1);

    // heads
    k_small<<<dim3(BATCH, HID / 64), 64, 0, stream>>>(h1last, lin_w, lin_b, feat, HID, HID);
    k_small<<<dim3(BATCH, 1), 64, 0, stream>>>(feat, out_w, out_b, lout, NCLS, HID);
    k_final<<<BATCH, 64, 0, stream>>>(match, lout, pred_w, pred_b, (float*)d_out);
}

// Round 6
// 1377.689 us; speedup vs baseline: 4.1448x; 1.6111x over previous
//
#include <hip/hip_runtime.h>
#include <hip/hip_bf16.h>
#include <hip/hip_fp16.h>
#include <math.h>

#define S_LEN 256
#define BATCH 64
#define EMB 300
#define HID 512
#define NCLS 46
#define NVAL 4
#define G4H 2048
#define EPSV 1e-8f

using half8   = __attribute__((ext_vector_type(8))) _Float16;
using floatx4 = __attribute__((ext_vector_type(4))) float;

__device__ __forceinline__ float fsigm(float x) { return 1.f / (1.f + __expf(-x)); }
__device__ __forceinline__ float ftanh(float x) {
    float e2 = __expf(-2.f * x);
    return (1.f - e2) / (1.f + e2);
}
__device__ __forceinline__ float h2f(unsigned short u) {
    union { unsigned short s; _Float16 h; } cv; cv.s = u; return (float)cv.h;
}
__device__ __forceinline__ half8 pack8(const float* p) {
    float4 f0 = *(const float4*)p;
    float4 f1 = *(const float4*)(p + 4);
    half8 h;
    h[0] = (_Float16)f0.x; h[1] = (_Float16)f0.y; h[2] = (_Float16)f0.z; h[3] = (_Float16)f0.w;
    h[4] = (_Float16)f1.x; h[5] = (_Float16)f1.y; h[6] = (_Float16)f1.z; h[7] = (_Float16)f1.w;
    return h;
}

// ---------------- label norms ----------------
__global__ void k_label_norm(const float* __restrict__ label, float* __restrict__ ln) {
    int r = blockIdx.x;
    int lane = threadIdx.x;
    const float* row = label + (size_t)r * EMB;
    float ss = 0.f;
    for (int e = lane; e < EMB; e += 64) { float v = row[e]; ss += v * v; }
    #pragma unroll
    for (int off = 32; off; off >>= 1) ss += __shfl_down(ss, off);
    if (lane == 0) ln[r] = sqrtf(ss);
}

// ---------------- gather embeddings + per-position norms ----------------
__global__ __launch_bounds__(256) void k_gather(const int* __restrict__ seq,
                                                const float* __restrict__ emb,
                                                float* __restrict__ embed,
                                                float* __restrict__ en) {
    int p = blockIdx.x * 4 + (threadIdx.x >> 6);
    int lane = threadIdx.x & 63;
    int row = seq[p];
    const float4* src = (const float4*)(emb + (size_t)row * EMB);
    float4* dst = (float4*)(embed + (size_t)p * EMB);
    float ss = 0.f;
    for (int e = lane; e < EMB / 4; e += 64) {
        float4 v = src[e];
        dst[e] = v;
        ss += v.x * v.x + v.y * v.y + v.z * v.z + v.w * v.w;
    }
    #pragma unroll
    for (int off = 32; off; off >>= 1) ss += __shfl_down(ss, off);
    if (lane == 0) en[p] = sqrtf(ss);
}

// ---------------- cosine similarity + max over (s, v) ----------------
__global__ __launch_bounds__(256) void k_cos(const float* __restrict__ embed,
                                             const float* __restrict__ en,
                                             const float* __restrict__ label,
                                             const float* __restrict__ ln,
                                             float* __restrict__ match) {
    int c = blockIdx.x, b = blockIdx.y;
    __shared__ float lab[NVAL][EMB];
    __shared__ float lns[NVAL];
    __shared__ float red[256];
    int tid = threadIdx.x;
    for (int i = tid; i < NVAL * EMB; i += 256) lab[i / EMB][i % EMB] = label[(size_t)c * NVAL * EMB + i];
    if (tid < NVAL) lns[tid] = ln[c * NVAL + tid];
    __syncthreads();
    int s = tid;
    const float4* erow = (const float4*)(embed + (size_t)(s * BATCH + b) * EMB);
    float d0 = 0, d1 = 0, d2 = 0, d3 = 0;
    for (int e = 0; e < EMB / 4; e++) {
        float4 v = erow[e];
        float4 l0 = *(const float4*)&lab[0][e * 4];
        float4 l1 = *(const float4*)&lab[1][e * 4];
        float4 l2 = *(const float4*)&lab[2][e * 4];
        float4 l3 = *(const float4*)&lab[3][e * 4];
        d0 += v.x * l0.x + v.y * l0.y + v.z * l0.z + v.w * l0.w;
        d1 += v.x * l1.x + v.y * l1.y + v.z * l1.z + v.w * l1.w;
        d2 += v.x * l2.x + v.y * l2.y + v.z * l2.z + v.w * l2.w;
        d3 += v.x * l3.x + v.y * l3.y + v.z * l3.z + v.w * l3.w;
    }
    float enb = en[s * BATCH + b];
    float m = d0 / fmaxf(enb * lns[0], EPSV);
    m = fmaxf(m, d1 / fmaxf(enb * lns[1], EPSV));
    m = fmaxf(m, d2 / fmaxf(enb * lns[2], EPSV));
    m = fmaxf(m, d3 / fmaxf(enb * lns[3], EPSV));
    red[tid] = m;
    __syncthreads();
    for (int st = 128; st; st >>= 1) {
        if (tid < st) red[tid] = fmaxf(red[tid], red[tid + st]);
        __syncthreads();
    }
    if (tid == 0) match[b * NCLS + c] = red[0];
}

// ---------------- big GEMM: Y(fp16) = X @ W^T + b1 + b2 ----------------
__global__ __launch_bounds__(256) void k_gemm_f16(const float* __restrict__ X,
                                                  const float* __restrict__ W,
                                                  const float* __restrict__ b1,
                                                  const float* __restrict__ b2,
                                                  unsigned short* __restrict__ Y,
                                                  int M, int N, int K) {
    __shared__ float Xs[16][132];
    __shared__ float Ws[16][132];
    int n0 = blockIdx.x * 128, m0 = blockIdx.y * 128;
    int tid = threadIdx.x;
    int tx = tid & 15, ty = tid >> 4;
    float acc[8][8] = {};
    for (int k0 = 0; k0 < K; k0 += 16) {
        #pragma unroll
        for (int i = 0; i < 8; i++) {
            int idx = i * 256 + tid;
            int r = idx >> 4, kk = idx & 15;
            int k = k0 + kk;
            Xs[kk][r] = (k < K) ? X[(size_t)(m0 + r) * K + k] : 0.f;
            Ws[kk][r] = (k < K) ? W[(size_t)(n0 + r) * K + k] : 0.f;
        }
        __syncthreads();
        #pragma unroll
        for (int kk = 0; kk < 16; kk++) {
            float a[8], w[8];
            *(float4*)&a[0] = *(const float4*)&Xs[kk][ty * 8];
            *(float4*)&a[4] = *(const float4*)&Xs[kk][ty * 8 + 4];
            *(float4*)&w[0] = *(const float4*)&Ws[kk][tx * 8];
            *(float4*)&w[4] = *(const float4*)&Ws[kk][tx * 8 + 4];
            #pragma unroll
            for (int i = 0; i < 8; i++)
                #pragma unroll
                for (int j = 0; j < 8; j++)
                    acc[i][j] += a[i] * w[j];
        }
        __syncthreads();
    }
    float bsum[8];
    #pragma unroll
    for (int j = 0; j < 8; j++) {
        int n = n0 + tx * 8 + j;
        bsum[j] = (b1 ? b1[n] : 0.f) + (b2 ? b2[n] : 0.f);
    }
    for (int i = 0; i < 8; i++) {
        unsigned short* yp = Y + (size_t)(m0 + ty * 8 + i) * N + n0 + tx * 8;
        #pragma unroll
        for (int j = 0; j < 8; j++) {
            union { _Float16 h; unsigned short s; } cv;
            cv.h = (_Float16)(acc[i][j] + bsum[j]);
            yp[j] = cv.s;
        }
    }
}

// ---------------- fused 2-layer pipelined persistent LSTM ----------------
// 192 blocks x 512 threads. XCD-local group g = bid&7 owns batches [g*8, g*8+8).
// Blocks 0..63:  layer 0, role r = bid>>3 owns 64 h-units (G0 precomputed, fp16).
// Blocks 64..191: layer 1, role rid = (bid-64)>>3 owns 32 h-units; computes its
// own input transform h0[t] @ w_ih1^T on the fly (w_ih1 fragments in VGPRs).
// L1 runs 1 step behind L0; h exchanged via fp16 rings in the group's XCD L2.
__global__ __launch_bounds__(512) void k_lstm_pipe(
    const float* __restrict__ w_hh0,
    const unsigned short* __restrict__ G0,   // [256][64][2048] fp16
    const float* __restrict__ w_ih1,
    const float* __restrict__ w_hh1,
    const float* __restrict__ b_ih1,
    const float* __restrict__ b_hh1,
    unsigned short* __restrict__ ring0,      // [256][64][512] fp16
    unsigned short* __restrict__ ring1,      // [256][64][512] fp16
    float* __restrict__ hlast,               // [64][512] fp32
    int* __restrict__ flags0,                // [64]
    int* __restrict__ flags1)                // [128]
{
    __shared__ __align__(16) char smem_raw[24576];
    int bid = blockIdx.x;
    int g = bid & 7;
    int tid = threadIdx.x;
    int w8 = tid >> 6, l = tid & 63, lj = l & 15, q8 = l >> 4;

    if (bid < 64) {
        // ================= LAYER 0 =================
        int r = bid >> 3;
        _Float16 (*hl)[520] = (_Float16(*)[520])smem_raw;
        float (*gbuf)[260] = (float(*)[260])(smem_raw + 8320);

        // B fragments (w_hh0): wave w8 owns local cols [w8*32, w8*32+32)
        half8 B0[16], B1[16];
        {
            int lc0 = w8 * 32 + lj;
            int lc1 = w8 * 32 + 16 + lj;
            int wr0 = (lc0 >> 6) * 512 + r * 64 + (lc0 & 63);
            int wr1 = (lc1 >> 6) * 512 + r * 64 + (lc1 & 63);
            #pragma unroll
            for (int kk = 0; kk < 16; kk++) {
                B0[kk] = pack8(w_hh0 + (size_t)wr0 * 512 + kk * 32 + q8 * 8);
                B1[kk] = pack8(w_hh0 + (size_t)wr1 * 512 + kk * 32 + q8 * 8);
            }
        }
        int gb_ = tid >> 6, gj = tid & 63;
        float cst = 0.f;

        for (int t = 0; t < S_LEN; t++) {
            const unsigned short* Gp = G0 + ((size_t)t * BATCH + g * 8 + gb_) * G4H + r * 64 + gj;
            float gv0 = h2f(Gp[0]), gv1 = h2f(Gp[512]), gv2 = h2f(Gp[1024]), gv3 = h2f(Gp[1536]);

            floatx4 acc0 = {0.f, 0.f, 0.f, 0.f}, acc1 = {0.f, 0.f, 0.f, 0.f};
            if (t > 0) {
                if (tid < 8) {
                    int gd = 1 << 20;
                    while (__hip_atomic_load(flags0 + g * 8 + tid, __ATOMIC_RELAXED,
                                             __HIP_MEMORY_SCOPE_AGENT) < t && --gd)
                        __builtin_amdgcn_s_sleep(1);
                }
                __syncthreads();
                {
                    int sb = tid >> 6, sk = (tid & 63) * 8;
                    const unsigned long long* src = (const unsigned long long*)
                        (ring0 + ((size_t)(t - 1) * BATCH + g * 8 + sb) * HID + sk);
                    unsigned long long v0 = __hip_atomic_load(src,     __ATOMIC_RELAXED, __HIP_MEMORY_SCOPE_AGENT);
                    unsigned long long v1 = __hip_atomic_load(src + 1, __ATOMIC_RELAXED, __HIP_MEMORY_SCOPE_AGENT);
                    *(unsigned long long*)&hl[sb][sk]     = v0;
                    *(unsigned long long*)&hl[sb][sk + 4] = v1;
                }
                __syncthreads();
                #pragma unroll
                for (int kk = 0; kk < 16; kk++) {
                    half8 A = *(const half8*)&hl[l & 7][kk * 32 + q8 * 8];
                    acc0 = __builtin_amdgcn_mfma_f32_16x16x32_f16(A, B0[kk], acc0, 0, 0, 0);
                    acc1 = __builtin_amdgcn_mfma_f32_16x16x32_f16(A, B1[kk], acc1, 0, 0, 0);
                }
                if (l < 32) {
                    #pragma unroll
                    for (int ri = 0; ri < 4; ri++) {
                        int row = q8 * 4 + ri;
                        gbuf[row][w8 * 32 + lj]      = acc0[ri];
                        gbuf[row][w8 * 32 + 16 + lj] = acc1[ri];
                    }
                }
                __syncthreads();
            }

            float s_i = gv0 + (t ? gbuf[gb_][gj]       : 0.f);
            float s_f = gv1 + (t ? gbuf[gb_][64 + gj]  : 0.f);
            float s_g = gv2 + (t ? gbuf[gb_][128 + gj] : 0.f);
            float s_o = gv3 + (t ? gbuf[gb_][192 + gj] : 0.f);
            cst = fsigm(s_f) * cst + fsigm(s_i) * ftanh(s_g);
            float hv = fsigm(s_o) * ftanh(cst);

            union { unsigned short s; _Float16 h; } cv; cv.h = (_Float16)hv;
            unsigned int mine = cv.s;
            unsigned int other = (unsigned int)__shfl_xor((int)mine, 1);
            if (!(gj & 1)) {
                unsigned int pk = (mine & 0xFFFFu) | (other << 16);
                unsigned int* rp = (unsigned int*)ring0;
                __hip_atomic_store(rp + (((size_t)t * BATCH + g * 8 + gb_) * HID + r * 64 + gj) / 2,
                                   pk, __ATOMIC_RELAXED, __HIP_MEMORY_SCOPE_AGENT);
            }
            __syncthreads();
            if (tid == 0)
                __hip_atomic_store(flags0 + g * 8 + r, t + 1, __ATOMIC_RELAXED, __HIP_MEMORY_SCOPE_AGENT);
        }
    } else {
        // ================= LAYER 1 =================
        int rid = (bid - 64) >> 3;
        _Float16 (*hl0)[520] = (_Float16(*)[520])smem_raw;
        _Float16 (*hl1)[520] = (_Float16(*)[520])(smem_raw + 8320);
        float (*gbuf)[132] = (float(*)[132])(smem_raw + 16640);

        // wave w8 owns N-tile w8: local cols [w8*16, w8*16+16)
        half8 Bin[16], Brec[16];
        {
            int gate = w8 >> 1;
            int wrow = gate * 512 + rid * 32 + (w8 & 1) * 16 + lj;
            #pragma unroll
            for (int kk = 0; kk < 16; kk++) {
                Bin[kk]  = pack8(w_ih1 + (size_t)wrow * 512 + kk * 32 + q8 * 8);
                Brec[kk] = pack8(w_hh1 + (size_t)wrow * 512 + kk * 32 + q8 * 8);
            }
        }
        float bi = 0.f, bf = 0.f, bgg = 0.f, bo = 0.f;
        if (tid < 256) {
            int u = tid & 31;
            int base = rid * 32 + u;
            bi  = b_ih1[base]        + b_hh1[base];
            bf  = b_ih1[512 + base]  + b_hh1[512 + base];
            bgg = b_ih1[1024 + base] + b_hh1[1024 + base];
            bo  = b_ih1[1536 + base] + b_hh1[1536 + base];
        }
        float cst = 0.f;

        for (int t = 0; t < S_LEN; t++) {
            // poll: h0[t] ready (all 8 L0 roles) and, for t>0, h1[t-1] ready (16 L1 roles)
            if (tid < 8) {
                int gd = 1 << 20;
                while (__hip_atomic_load(flags0 + g * 8 + tid, __ATOMIC_RELAXED,
                                         __HIP_MEMORY_SCOPE_AGENT) < t + 1 && --gd)
                    __builtin_amdgcn_s_sleep(1);
            } else if (tid < 24 && t > 0) {
                int gd = 1 << 20;
                while (__hip_atomic_load(flags1 + g * 16 + (tid - 8), __ATOMIC_RELAXED,
                                         __HIP_MEMORY_SCOPE_AGENT) < t && --gd)
                    __builtin_amdgcn_s_sleep(1);
            }
            __syncthreads();

            {
                int sb = tid >> 6, sk = (tid & 63) * 8;
                const unsigned long long* s0 = (const unsigned long long*)
                    (ring0 + ((size_t)t * BATCH + g * 8 + sb) * HID + sk);
                unsigned long long v0 = __hip_atomic_load(s0,     __ATOMIC_RELAXED, __HIP_MEMORY_SCOPE_AGENT);
                unsigned long long v1 = __hip_atomic_load(s0 + 1, __ATOMIC_RELAXED, __HIP_MEMORY_SCOPE_AGENT);
                *(unsigned long long*)&hl0[sb][sk]     = v0;
                *(unsigned long long*)&hl0[sb][sk + 4] = v1;
                if (t > 0) {
                    const unsigned long long* s1 = (const unsigned long long*)
                        (ring1 + ((size_t)(t - 1) * BATCH + g * 8 + sb) * HID + sk);
                    unsigned long long u0 = __hip_atomic_load(s1,     __ATOMIC_RELAXED, __HIP_MEMORY_SCOPE_AGENT);
                    unsigned long long u1 = __hip_atomic_load(s1 + 1, __ATOMIC_RELAXED, __HIP_MEMORY_SCOPE_AGENT);
                    *(unsigned long long*)&hl1[sb][sk]     = u0;
                    *(unsigned long long*)&hl1[sb][sk + 4] = u1;
                }
            }
            __syncthreads();

            floatx4 accA = {0.f, 0.f, 0.f, 0.f}, accB = {0.f, 0.f, 0.f, 0.f};
            #pragma unroll
            for (int kk = 0; kk < 16; kk++) {
                half8 A0 = *(const half8*)&hl0[l & 7][kk * 32 + q8 * 8];
                accA = __builtin_amdgcn_mfma_f32_16x16x32_f16(A0, Bin[kk], accA, 0, 0, 0);
            }
            if (t > 0) {
                #pragma unroll
                for (int kk = 0; kk < 16; kk++) {
                    half8 A1 = *(const half8*)&hl1[l & 7][kk * 32 + q8 * 8];
                    accB = __builtin_amdgcn_mfma_f32_16x16x32_f16(A1, Brec[kk], accB, 0, 0, 0);
                }
            }
            if (l < 32) {
                #pragma unroll
                for (int ri = 0; ri < 4; ri++) {
                    int row = q8 * 4 + ri;
                    gbuf[row][w8 * 16 + lj] = accA[ri] + accB[ri];
                }
            }
            __syncthreads();

            if (tid < 256) {
                int b = tid >> 5, u = tid & 31;
                float s_i = gbuf[b][u]      + bi;
                float s_f = gbuf[b][32 + u] + bf;
                float s_g = gbuf[b][64 + u] + bgg;
                float s_o = gbuf[b][96 + u] + bo;
                cst = fsigm(s_f) * cst + fsigm(s_i) * ftanh(s_g);
                float hv = fsigm(s_o) * ftanh(cst);

                union { unsigned short s; _Float16 h; } cv; cv.h = (_Float16)hv;
                unsigned int mine = cv.s;
                unsigned int other = (unsigned int)__shfl_xor((int)mine, 1);
                if (!(u & 1)) {
                    unsigned int pk = (mine & 0xFFFFu) | (other << 16);
                    unsigned int* rp = (unsigned int*)ring1;
                    __hip_atomic_store(rp + (((size_t)t * BATCH + g * 8 + b) * HID + rid * 32 + u) / 2,
                                       pk, __ATOMIC_RELAXED, __HIP_MEMORY_SCOPE_AGENT);
                }
                if (t == S_LEN - 1)
                    hlast[(g * 8 + b) * HID + rid * 32 + u] = hv;
            }
            __syncthreads();
            if (tid == 0)
                __hip_atomic_store(flags1 + g * 16 + rid, t + 1, __ATOMIC_RELAXED, __HIP_MEMORY_SCOPE_AGENT);
        }
    }
}

// ---------------- small GEMM ----------------
__global__ void k_small(const float* __restrict__ X, const float* __restrict__ W,
                        const float* __restrict__ bias, float* __restrict__ Y,
                        int N, int K) {
    int m = blockIdx.x;
    int n = blockIdx.y * 64 + threadIdx.x;
    if (n >= N) return;
    const float* x = X + (size_t)m * K;
    const float* w = W + (size_t)n * K;
    float s = bias[n];
    for (int k = 0; k < K; k++) s += x[k] * w[k];
    Y[(size_t)m * N + n] = s;
}

// ---------------- final head ----------------
__global__ void k_final(const float* __restrict__ match, const float* __restrict__ lout,
                        const float* __restrict__ W, const float* __restrict__ bias,
                        float* __restrict__ out) {
    int m = blockIdx.x;
    int n = threadIdx.x;
    if (n >= NCLS) return;
    const float* w = W + (size_t)n * (2 * NCLS);
    float s = bias[n];
    for (int k = 0; k < NCLS; k++) s += match[m * NCLS + k] * w[k];
    for (int k = 0; k < NCLS; k++) s += lout[m * NCLS + k] * w[NCLS + k];
    out[m * NCLS + n] = s;
}

extern "C" void kernel_launch(void* const* d_in, const int* in_sizes, int n_in,
                              void* d_out, int out_size, void* d_ws, size_t ws_size,
                              hipStream_t stream) {
    (void)in_sizes; (void)n_in; (void)out_size; (void)ws_size;
    const int*   seq    = (const int*)d_in[0];
    const float* emb    = (const float*)d_in[1];
    const float* w_ih0  = (const float*)d_in[2];
    const float* w_hh0  = (const float*)d_in[3];
    const float* b_ih0  = (const float*)d_in[4];
    const float* b_hh0  = (const float*)d_in[5];
    const float* w_ih1  = (const float*)d_in[6];
    const float* w_hh1  = (const float*)d_in[7];
    const float* b_ih1  = (const float*)d_in[8];
    const float* b_hh1  = (const float*)d_in[9];
    const float* lin_w  = (const float*)d_in[10];
    const float* lin_b  = (const float*)d_in[11];
    const float* out_w  = (const float*)d_in[12];
    const float* out_b  = (const float*)d_in[13];
    const float* pred_w = (const float*)d_in[14];
    const float* pred_b = (const float*)d_in[15];
    const float* label  = (const float*)d_in[16];

    float* ws = (float*)d_ws;
    size_t o = 0;
    float* embed = ws + o; o += (size_t)S_LEN * BATCH * EMB;        // 19.7 MB
    unsigned short* G0 = (unsigned short*)(ws + o); o += (size_t)S_LEN * BATCH * G4H / 2;     // fp16, 67 MB
    unsigned short* ring0 = (unsigned short*)(ws + o); o += (size_t)S_LEN * BATCH * HID / 2;  // fp16
    unsigned short* ring1 = (unsigned short*)(ws + o); o += (size_t)S_LEN * BATCH * HID / 2;  // fp16
    float* h1last = ws + o; o += (size_t)BATCH * HID;
    float* en    = ws + o; o += S_LEN * BATCH;
    float* ln    = ws + o; o += 256;
    float* match = ws + o; o += 3072;
    float* feat  = ws + o; o += (size_t)BATCH * HID;
    float* lout  = ws + o; o += 3072;
    int*   flags0 = (int*)(ws + o); o += 64;
    int*   flags1 = (int*)(ws + o); o += 128;

    hipMemsetAsync(flags0, 0, 192 * sizeof(int), stream);

    k_label_norm<<<NCLS * NVAL, 64, 0, stream>>>(label, ln);
    k_gather<<<S_LEN * BATCH / 4, 256, 0, stream>>>(seq, emb, embed, en);
    k_cos<<<dim3(NCLS, BATCH), 256, 0, stream>>>(embed, en, label, ln, match);

    // layer-0 input transform (fp16 out)
    k_gemm_f16<<<dim3(G4H / 128, S_LEN * BATCH / 128), 256, 0, stream>>>(
        embed, w_ih0, b_ih0, b_hh0, G0, S_LEN * BATCH, G4H, EMB);

    // fused pipelined 2-layer recurrence
    k_lstm_pipe<<<192, 512, 0, stream>>>(w_hh0, G0, w_ih1, w_hh1, b_ih1, b_hh1,
                                         ring0, ring1, h1last, flags0, flags1);

    // heads
    k_small<<<dim3(BATCH, HID / 64), 64, 0, stream>>>(h1last, lin_w, lin_b, feat, HID, HID);
    k_small<<<dim3(BATCH, 1), 64, 0, stream>>>(feat, out_w, out_b, lout, NCLS, HID);
    k_final<<<BATCH, 64, 0, stream>>>(match, lout, pred_w, pred_b, (float*)d_out);
}